// Round 11
// baseline (428.961 us; speedup 1.0000x reference)
//
#include <hip/hip_runtime.h>
#include <hip/hip_bf16.h>

// Problem constants
#define NGRAPH 16384
#define NPAIR  (NGRAPH / 2)
#define NG     23
#define PCOLS  46             // 2*NG node columns per pair
#define HD     64
#define INF    8
#define LAYERS 20
#define EDGES_PER 256
#define E_TOT  (NGRAPH * EDGES_PER)
#define BATCH  1024
#define TWIN   16
#define CLS    3

// ztr: dim-major z buffer, NS node slots/dim. Element (d, n) stored at
//   d*NS + ((n>>3) ^ ((d>>1)&7))*8 + (n&7)
// XOR chunk swizzle: za b128 reads bank-uniform, b16 scatter ~2-way (free).
#define NS 64

typedef __attribute__((ext_vector_type(8))) short s8v;   // 8 bf16 MFMA A/B frag
typedef __attribute__((ext_vector_type(4))) float f4v;   // 4 fp32 MFMA C/D frag
typedef __attribute__((ext_vector_type(2))) float f2v;   // packed-fp32 pair

union FragU { unsigned u[4]; s8v v; };

__device__ inline f2v vlo(f4v v) { return (f2v){v[0], v[1]}; }
__device__ inline f2v vhi(f4v v) { return (f2v){v[2], v[3]}; }

// HW RNE f32x2 -> bf16x2 (r7-verified; memcpy because __hip_bfloat162 is not
// trivially copyable on this ROCm)
__device__ inline unsigned pk2_bf16(f2v v) {
  __hip_bfloat162 b = __float22bfloat162_rn(make_float2(v[0], v[1]));
  unsigned r;
  __builtin_memcpy(&r, &b, sizeof(r));
  return r;
}

__device__ inline f2v max0(f2v v) {
#if defined(__has_builtin) && __has_builtin(__builtin_elementwise_max)
  return __builtin_elementwise_max(v, (f2v){0.f, 0.f});
#else
  return (f2v){fmaxf(v[0], 0.f), fmaxf(v[1], 0.f)};
#endif
}

// manual RNE pack (prep kernels only)
__device__ inline unsigned f2bf_pk(float a, float b) {
  unsigned ua = __builtin_bit_cast(unsigned, a);
  unsigned ub = __builtin_bit_cast(unsigned, b);
  ua = ua + 0x7FFFu + ((ua >> 16) & 1u);
  ub = ub + 0x7FFFu + ((ub >> 16) & 1u);
  return (ua >> 16) | (ub & 0xFFFF0000u);
}

// ---------------------------------------------------------------------------
// Kernel 1: pack W^T into A-frag order, permuted k-mapping (r5-verified):
// k-slot (Kt, quad, j) holds dim_in = ((j>>2)*2+Kt)*16 + quad*4 + (j&3).
// ---------------------------------------------------------------------------
__global__ __launch_bounds__(256) void pack_w(const float* __restrict__ W_rel,
                                              const float* __restrict__ W_root,
                                              unsigned* __restrict__ wf) {
  const int tid = blockIdx.x * 256 + threadIdx.x;
  if (tid >= LAYERS * 2 * 4 * 2 * 64) return;
  const int lane = tid & 63, fi = tid >> 6;
  const int Kt = fi & 1, Mt = (fi >> 1) & 3, m = (fi >> 3) & 1, l = fi >> 4;
  const float* W = (m ? W_root : W_rel) + (size_t)l * HD * HD;
  const int col = lane & 15, quad = lane >> 4;
  const int jdim = Mt * 16 + col;
  unsigned pk[4];
#pragma unroll
  for (int w = 0; w < 4; ++w) {
    const int j0 = 2 * w, j1 = 2 * w + 1;
    const int d0 = ((j0 >> 2) * 2 + Kt) * 16 + quad * 4 + (j0 & 3);
    const int d1 = ((j1 >> 2) * 2 + Kt) * 16 + quad * 4 + (j1 & 3);
    pk[w] = f2bf_pk(W[(size_t)d0 * HD + jdim], W[(size_t)d1 * HD + jdim]);
  }
  uint4 q; q.x = pk[0]; q.y = pk[1]; q.z = pk[2]; q.w = pk[3];
  *(uint4*)&wf[(size_t)tid * 4] = q;
}

// ---------------------------------------------------------------------------
// Kernel 2: pair adjacency -> B-frags in GLOBAL (r10 prologue A/B verbatim,
// retargeted). Frees 24 whole-kernel-lived regs in gcn_main.
// ---------------------------------------------------------------------------
__global__ __launch_bounds__(256) void build_padj(const int* __restrict__ ei,
                                                  unsigned* __restrict__ adjf) {
  __shared__ unsigned cnt[4][48 * 24];
  const int lane = threadIdx.x & 63, wv = threadIdx.x >> 6;
  const int p = blockIdx.x * 4 + wv;
  const int col = lane & 15, quad = lane >> 4;
  unsigned* c = cnt[wv];
  for (int i = lane; i < 48 * 24; i += 64) c[i] = 0;
  asm volatile("s_waitcnt lgkmcnt(0)" ::: "memory");
  const int ebase = p * (2 * EDGES_PER);
  const int noff = p * PCOLS;
#pragma unroll
  for (int r = 0; r < 8; ++r) {
    const int e = ebase + r * 64 + lane;
    const int s = ei[e] - noff;           // src pair-col 0..45
    const int d = ei[E_TOT + e] - noff;   // dst pair-col 0..45
    atomicAdd(&c[d * 24 + (s >> 1)], 1u << ((s & 1) * 16));
  }
  asm volatile("s_waitcnt lgkmcnt(0)" ::: "memory");
#pragma unroll
  for (int Nt = 0; Nt < 3; ++Nt) {
    const int dst = col + 16 * Nt;
    const bool dok = dst < PCOLS;
#pragma unroll
    for (int Kt = 0; Kt < 2; ++Kt) {
      unsigned pk[4];
#pragma unroll
      for (int w = 0; w < 4; ++w) {
        const int s0 = Kt * 32 + quad * 8 + 2 * w;
        float v0 = 0.f, v1 = 0.f;
        if (dok && s0 < PCOLS) {
          const unsigned rd = c[dst * 24 + (s0 >> 1)];
          v0 = (float)(rd & 0xffffu);
          if (s0 + 1 < PCOLS) v1 = (float)(rd >> 16);
        }
        pk[w] = f2bf_pk(v0, v1);
      }
      uint4 q; q.x = pk[0]; q.y = pk[1]; q.z = pk[2]; q.w = pk[3];
      ((uint4*)adjf)[((size_t)p * 6 + Nt * 2 + Kt) * 64 + lane] = q;
    }
  }
}

// ---------------------------------------------------------------------------
// Kernel 3: wave = 1 graph PAIR; __launch_bounds__(256,4). r10 structure with
// the two liveness cuts: (a) adjacency loaded per layer AFTER Wo-GEMM issue
// (transient), (b) per-Nt agA/agC death in the agg phase (peak ag 24 -> 8).
// ---------------------------------------------------------------------------
__global__ __launch_bounds__(256, 4) void gcn_main(
    const float* __restrict__ x, const unsigned* __restrict__ adjf,
    const unsigned* __restrict__ wf,
    const float* __restrict__ W_enc, const float* __restrict__ b_enc,
    const float* __restrict__ ln_g, const float* __restrict__ ln_b,
    const float* __restrict__ b_rel, float* __restrict__ pooled) {
  __shared__ __align__(16) unsigned short sm[4 * HD * NS];   // 32768 B/block
  const int lane = threadIdx.x & 63, wv = threadIdx.x >> 6;
  const int p = blockIdx.x * 4 + wv;                         // pair id
  const int col = lane & 15, quad = lane >> 4;
  unsigned short* zt = sm + wv * (HD * NS);                  // 8192 B / wave

  // ---- prologue: zero ztr (pad slots must stay exact bf16 zero) ----
  {
    uint4 z4; z4.x = 0; z4.y = 0; z4.z = 0; z4.w = 0;
    for (int i = lane; i < (HD * NS * 2) / 16; i += 64) ((uint4*)zt)[i] = z4;
  }
  asm volatile("s_waitcnt lgkmcnt(0)" ::: "memory");

  // adjacency frag base pointers (loop-invariant; imm offsets stay <= 4095 B)
  const uint4* ap  = (const uint4*)adjf + (size_t)p * 384 + lane;  // frags 0-3
  const uint4* ap4 = ap + 256;                                     // frags 4-5

  // ---- compact loop-invariant ztr addresses (u16 units) ----
  const int c7 = (col >> 1) & 7;
  const int ra0 = col * NS + ((quad ^ c7) << 3);
  const unsigned short* zA = zt + ra0;
  const unsigned short* zB = zt + (ra0 ^ 32);
  int wb[3][2];
#pragma unroll
  for (int Nt = 0; Nt < 3; ++Nt) {
    const int node = col + 16 * Nt;
    wb[Nt][0] = (quad * 4    ) * NS + (((node >> 3) ^ (quad * 2    )) << 3) + (node & 7);
    wb[Nt][1] = (quad * 4 + 2) * NS + (((node >> 3) ^ (quad * 2 + 1)) << 3) + (node & 7);
  }

  // ---- encoder: pair x rows contiguous (node_id = p*46 + paircol) ----
  f4v acc[4][3];
  {
    const float* xg = x + (size_t)p * PCOLS * INF;
    f4v xa[3][2];
    const f4v zz = {0.f, 0.f, 0.f, 0.f};
#pragma unroll
    for (int Nt = 0; Nt < 3; ++Nt) {
      const int c = col + 16 * Nt;
      if (c < PCOLS) {
        const float* xp = xg + (size_t)c * INF;
        xa[Nt][0] = *(const f4v*)xp;
        xa[Nt][1] = *(const f4v*)(xp + 4);
      } else { xa[Nt][0] = zz; xa[Nt][1] = zz; }
    }
#pragma unroll
    for (int Mt = 0; Mt < 4; ++Mt) {
      const f4v be = *(const f4v*)(b_enc + Mt * 16 + quad * 4);
      acc[Mt][0] = be; acc[Mt][1] = be; acc[Mt][2] = be;
#pragma unroll
      for (int i = 0; i < INF; ++i) {
        const f4v we = *(const f4v*)(W_enc + i * HD + Mt * 16 + quad * 4);
        acc[Mt][0] += we * xa[0][i >> 2][i & 3];
        acc[Mt][1] += we * xa[1][i >> 2][i & 3];
        acc[Mt][2] += we * xa[2][i >> 2][i & 3];
      }
    }
  }

#pragma unroll 1
  for (int l = 0; l < LAYERS; ++l) {
    const unsigned* wbase = wf + (size_t)l * (2 * 4 * 2 * 64 * 4);

    // ---- LayerNorm: one-pass E[h], E[h^2], 6 interleaved chains ----
    float mu[3], rs[3];
    {
      float sh[3], qh[3];
#pragma unroll
      for (int Nt = 0; Nt < 3; ++Nt) {
        f2v t = vlo(acc[0][Nt]) + vhi(acc[0][Nt]);
        t += vlo(acc[1][Nt]); t += vhi(acc[1][Nt]);
        t += vlo(acc[2][Nt]); t += vhi(acc[2][Nt]);
        t += vlo(acc[3][Nt]); t += vhi(acc[3][Nt]);
        f2v u = vlo(acc[0][Nt]) * vlo(acc[0][Nt]);
        u += vhi(acc[0][Nt]) * vhi(acc[0][Nt]);
        u += vlo(acc[1][Nt]) * vlo(acc[1][Nt]);
        u += vhi(acc[1][Nt]) * vhi(acc[1][Nt]);
        u += vlo(acc[2][Nt]) * vlo(acc[2][Nt]);
        u += vhi(acc[2][Nt]) * vhi(acc[2][Nt]);
        u += vlo(acc[3][Nt]) * vlo(acc[3][Nt]);
        u += vhi(acc[3][Nt]) * vhi(acc[3][Nt]);
        sh[Nt] = t[0] + t[1];
        qh[Nt] = u[0] + u[1];
      }
#pragma unroll
      for (int Nt = 0; Nt < 3; ++Nt) { sh[Nt] += __shfl_xor(sh[Nt], 16); qh[Nt] += __shfl_xor(qh[Nt], 16); }
#pragma unroll
      for (int Nt = 0; Nt < 3; ++Nt) { sh[Nt] += __shfl_xor(sh[Nt], 32); qh[Nt] += __shfl_xor(qh[Nt], 32); }
#pragma unroll
      for (int Nt = 0; Nt < 3; ++Nt) {
        mu[Nt] = sh[Nt] * (1.0f / HD);
        float var = fmaf(qh[Nt], (1.0f / HD), -mu[Nt] * mu[Nt]);
        var = fmaxf(var, 0.f);
        rs[Nt] = rsqrtf(var + 1e-5f);
      }
    }

    // ---- z = relu(LN(h)) -> zpk B-frags (k-permuted) + ztr scatter ----
    FragU zpk[2][3];
#pragma unroll
    for (int Kt = 0; Kt < 2; ++Kt) {
#pragma unroll
      for (int hi = 0; hi < 2; ++hi) {
        const int Mt = Kt + 2 * hi;
        const f4v gf  = *(const f4v*)(ln_g + l * HD + Mt * 16 + quad * 4);
        const f4v bfv = *(const f4v*)(ln_b + l * HD + Mt * 16 + quad * 4);
        const f2v gl = vlo(gf), gh = vhi(gf);
        const f2v bl = vlo(bfv), bh = vhi(bfv);
#pragma unroll
        for (int Nt = 0; Nt < 3; ++Nt) {
          const f2v sgl = gl * rs[Nt], sgh = gh * rs[Nt];
          const f2v tbl = bl - mu[Nt] * sgl, tbh = bh - mu[Nt] * sgh;
          const f2v zl = max0(vlo(acc[Mt][Nt]) * sgl + tbl);
          const f2v zh = max0(vhi(acc[Mt][Nt]) * sgh + tbh);
          zpk[Kt][Nt].u[hi * 2 + 0] = pk2_bf16(zl);
          zpk[Kt][Nt].u[hi * 2 + 1] = pk2_bf16(zh);
        }
      }
#pragma unroll
      for (int hi = 0; hi < 2; ++hi) {
        const int Mt = Kt + 2 * hi;
#pragma unroll
        for (int Nt = 0; Nt < 3; ++Nt)
#pragma unroll
          for (int r2 = 0; r2 < 2; ++r2) {
            const unsigned d = zpk[Kt][Nt].u[hi * 2 + r2];
            unsigned short* pz = zt + Mt * 1024 + wb[Nt][r2];
            pz[0]  = (unsigned short)d;
            pz[NS] = (unsigned short)(d >> 16);
          }
      }
    }

    // ---- Wo-GEMM (register B; overlaps ztr round-trip) ----
#pragma unroll
    for (int Kt = 0; Kt < 2; ++Kt)
#pragma unroll
      for (int Mt = 0; Mt < 4; ++Mt) {
        const s8v wo = *(const s8v*)&wbase[((((1 * 4) + Mt) * 2 + Kt) * 64 + lane) * 4];
#pragma unroll
        for (int Nt = 0; Nt < 3; ++Nt)
          acc[Mt][Nt] = __builtin_amdgcn_mfma_f32_16x16x32_bf16(wo, zpk[Kt][Nt].v, acc[Mt][Nt], 0, 0, 0);
      }

    // ---- adjacency B-frags: issued AFTER wo loads (in-order vmcnt never
    //      stalls Wo on these); live only across the agg phase ----
    FragU adjB[3][2];
#pragma unroll
    for (int idx = 0; idx < 4; ++idx)
      adjB[idx >> 1][idx & 1].v = *(const s8v*)(ap + idx * 64);
    adjB[2][0].v = *(const s8v*)(ap4);
    adjB[2][1].v = *(const s8v*)(ap4 + 64);

    asm volatile("s_waitcnt lgkmcnt(0)" ::: "memory");

    // ---- agg + pack per Nt (ag dies immediately), then Wr-GEMM ----
    const f4v zzero = {0.f, 0.f, 0.f, 0.f};
#pragma unroll
    for (int Kt = 0; Kt < 2; ++Kt) {
      const s8v zaA0 = *(const s8v*)&zA[(Kt    ) * 1024];
      const s8v zaA1 = *(const s8v*)&zB[(Kt    ) * 1024];
      const s8v zaC0 = *(const s8v*)&zA[(Kt + 2) * 1024];
      const s8v zaC1 = *(const s8v*)&zB[(Kt + 2) * 1024];
      FragU apk[3];
#pragma unroll
      for (int Nt = 0; Nt < 3; ++Nt) {
        f4v agA = __builtin_amdgcn_mfma_f32_16x16x32_bf16(zaA0, adjB[Nt][0].v, zzero, 0, 0, 0);
        agA     = __builtin_amdgcn_mfma_f32_16x16x32_bf16(zaA1, adjB[Nt][1].v, agA,   0, 0, 0);
        f4v agC = __builtin_amdgcn_mfma_f32_16x16x32_bf16(zaC0, adjB[Nt][0].v, zzero, 0, 0, 0);
        agC     = __builtin_amdgcn_mfma_f32_16x16x32_bf16(zaC1, adjB[Nt][1].v, agC,   0, 0, 0);
        apk[Nt].u[0] = pk2_bf16(vlo(agA));
        apk[Nt].u[1] = pk2_bf16(vhi(agA));
        apk[Nt].u[2] = pk2_bf16(vlo(agC));
        apk[Nt].u[3] = pk2_bf16(vhi(agC));
      }
#pragma unroll
      for (int Mt = 0; Mt < 4; ++Mt) {
        const s8v wr = *(const s8v*)&wbase[((((0 * 4) + Mt) * 2 + Kt) * 64 + lane) * 4];
#pragma unroll
        for (int Nt = 0; Nt < 3; ++Nt)
          acc[Mt][Nt] = __builtin_amdgcn_mfma_f32_16x16x32_bf16(wr, apk[Nt].v, acc[Mt][Nt], 0, 0, 0);
      }
    }

    // ---- + b_rel ----
#pragma unroll
    for (int Mt = 0; Mt < 4; ++Mt) {
      const f4v brf = *(const f4v*)(b_rel + l * HD + Mt * 16 + quad * 4);
      const f2v bl = vlo(brf), bh = vhi(brf);
#pragma unroll
      for (int Nt = 0; Nt < 3; ++Nt) {
        const f2v al = vlo(acc[Mt][Nt]) + bl;
        const f2v ah = vhi(acc[Mt][Nt]) + bh;
        acc[Mt][Nt] = (f4v){al[0], al[1], ah[0], ah[1]};
      }
    }
  }

  // ---- pool: two graphs per pair, two-pass through the 8 KB ztr region ----
  float* hb = (float*)zt;   // 32 cols x 64 dims x 4B = 8192 B exactly
  asm volatile("s_waitcnt lgkmcnt(0)" ::: "memory");
#pragma unroll
  for (int Mt = 0; Mt < 4; ++Mt)
#pragma unroll
    for (int Nt = 0; Nt < 2; ++Nt)
      *(f4v*)&hb[(col + 16 * Nt) * HD + Mt * 16 + quad * 4] = acc[Mt][Nt];
  asm volatile("s_waitcnt lgkmcnt(0)" ::: "memory");
  float sA = 0.f, sB = 0.f;
#pragma unroll
  for (int c = 0; c < NG; ++c) sA += hb[c * HD + lane];          // cols 0-22 (gA)
#pragma unroll
  for (int c = NG; c < 32; ++c) sB += hb[c * HD + lane];         // cols 23-31
  asm volatile("s_waitcnt lgkmcnt(0)" ::: "memory");
#pragma unroll
  for (int Mt = 0; Mt < 4; ++Mt)                                 // cols 32-47 -> slots 0-15
    *(f4v*)&hb[col * HD + Mt * 16 + quad * 4] = acc[Mt][2];
  asm volatile("s_waitcnt lgkmcnt(0)" ::: "memory");
#pragma unroll
  for (int c = 0; c < PCOLS - 32; ++c) sB += hb[c * HD + lane];  // cols 32-45
  pooled[(size_t)(2 * p) * HD + lane] = sA;
  pooled[(size_t)(2 * p + 1) * HD + lane] = sB;
}

// ---------------------------------------------------------------------------
// Kernel 4: temporal mean (+pos) + MLP head (unchanged, verified)
// ---------------------------------------------------------------------------
__global__ __launch_bounds__(64) void head(
    const float* __restrict__ pooled, const float* __restrict__ pos,
    const float* __restrict__ W1, const float* __restrict__ b1,
    const float* __restrict__ W2, const float* __restrict__ b2,
    float* __restrict__ out) {
  __shared__ float sv[HD];
  __shared__ float sh1[HD];
  const int b = blockIdx.x, k = threadIdx.x;
  float v = 0.f;
#pragma unroll
  for (int tt = 0; tt < TWIN; ++tt) v += pooled[((size_t)(b * TWIN + tt)) * HD + k];
  float p = 0.f;
#pragma unroll
  for (int tt = 0; tt < TWIN; ++tt) p += pos[tt * HD + k];
  v = v * (1.0f / (NG * TWIN)) + p * (1.0f / TWIN);
  sv[k] = v;
  __syncthreads();
  float a = b1[k];
#pragma unroll
  for (int kk = 0; kk < HD; ++kk) a = fmaf(sv[kk], W1[kk * HD + k], a);
  a = fmaxf(a, 0.f);
  sh1[k] = a;
  __syncthreads();
  if (k < CLS) {
    float o = b2[k];
#pragma unroll
    for (int kk = 0; kk < HD; ++kk) o = fmaf(sh1[kk], W2[kk * CLS + k], o);
    out[(size_t)b * CLS + k] = o;
  }
}

// ---------------------------------------------------------------------------
extern "C" void kernel_launch(void* const* d_in, const int* in_sizes, int n_in,
                              void* d_out, int out_size, void* d_ws, size_t ws_size,
                              hipStream_t stream) {
  const float* x      = (const float*)d_in[0];
  const int*   ei     = (const int*)  d_in[1];
  const float* W_enc  = (const float*)d_in[3];
  const float* b_enc  = (const float*)d_in[4];
  const float* ln_g   = (const float*)d_in[5];
  const float* ln_b   = (const float*)d_in[6];
  const float* W_rel  = (const float*)d_in[7];
  const float* b_rel  = (const float*)d_in[8];
  const float* W_root = (const float*)d_in[9];
  const float* pos    = (const float*)d_in[10];
  const float* W1     = (const float*)d_in[11];
  const float* b1     = (const float*)d_in[12];
  const float* W2     = (const float*)d_in[13];
  const float* b2     = (const float*)d_in[14];
  float* out = (float*)d_out;

  // workspace: W frags 320 KB | pair adj frags 50.3 MB | pooled 4.2 MB
  char* pp = (char*)d_ws;
  unsigned* wfrag   = (unsigned*)pp;  pp += (size_t)LAYERS * 2 * 4 * 2 * 64 * 16;
  unsigned* adjfrag = (unsigned*)pp;  pp += (size_t)NPAIR * 6 * 64 * 16;
  float*    pooled  = (float*)pp;

  pack_w    <<<80, 256, 0, stream>>>(W_rel, W_root, wfrag);
  build_padj<<<NPAIR / 4, 256, 0, stream>>>(ei, adjfrag);
  gcn_main  <<<NPAIR / 4, 256, 0, stream>>>(x, adjfrag, wfrag, W_enc, b_enc,
                                            ln_g, ln_b, b_rel, pooled);
  head      <<<BATCH, 64, 0, stream>>>(pooled, pos, W1, b1, W2, b2, out);
}

// Round 12
// 420.218 us; speedup vs baseline: 1.0208x; 1.0208x over previous
//
#include <hip/hip_runtime.h>
#include <hip/hip_bf16.h>

// Problem constants
#define NGRAPH 16384
#define NPAIR  (NGRAPH / 2)
#define NG     23
#define PCOLS  46             // 2*NG node columns per pair
#define HD     64
#define INF    8
#define LAYERS 20
#define EDGES_PER 256
#define E_TOT  (NGRAPH * EDGES_PER)
#define BATCH  1024
#define TWIN   16
#define CLS    3

// ztr: dim-major z buffer, NS node slots/dim. Element (d, n) stored at
//   d*NS + ((n>>3) ^ ((d>>1)&7))*8 + (n&7)
// XOR chunk swizzle: za b128 reads bank-uniform, b16 scatter ~2-way (free).
#define NS 64

typedef __attribute__((ext_vector_type(8))) short s8v;   // 8 bf16 MFMA A/B frag
typedef __attribute__((ext_vector_type(4))) float f4v;   // 4 fp32 MFMA C/D frag
typedef __attribute__((ext_vector_type(2))) float f2v;   // packed-fp32 pair

union FragU { unsigned u[4]; s8v v; };

__device__ inline f2v vlo(f4v v) { return (f2v){v[0], v[1]}; }
__device__ inline f2v vhi(f4v v) { return (f2v){v[2], v[3]}; }

// HW RNE f32x2 -> bf16x2 (r7-verified; memcpy because __hip_bfloat162 is not
// trivially copyable on this ROCm)
__device__ inline unsigned pk2_bf16(f2v v) {
  __hip_bfloat162 b = __float22bfloat162_rn(make_float2(v[0], v[1]));
  unsigned r;
  __builtin_memcpy(&r, &b, sizeof(r));
  return r;
}

__device__ inline f2v max0(f2v v) {
#if defined(__has_builtin) && __has_builtin(__builtin_elementwise_max)
  return __builtin_elementwise_max(v, (f2v){0.f, 0.f});
#else
  return (f2v){fmaxf(v[0], 0.f), fmaxf(v[1], 0.f)};
#endif
}

// manual RNE pack (prep kernels only)
__device__ inline unsigned f2bf_pk(float a, float b) {
  unsigned ua = __builtin_bit_cast(unsigned, a);
  unsigned ub = __builtin_bit_cast(unsigned, b);
  ua = ua + 0x7FFFu + ((ua >> 16) & 1u);
  ub = ub + 0x7FFFu + ((ub >> 16) & 1u);
  return (ua >> 16) | (ub & 0xFFFF0000u);
}

// ---------------------------------------------------------------------------
// Kernel 1: pack W^T into A-frag order, permuted k-mapping (r5-verified):
// k-slot (Kt, quad, j) holds dim_in = ((j>>2)*2+Kt)*16 + quad*4 + (j&3).
// ---------------------------------------------------------------------------
__global__ __launch_bounds__(256) void pack_w(const float* __restrict__ W_rel,
                                              const float* __restrict__ W_root,
                                              unsigned* __restrict__ wf) {
  const int tid = blockIdx.x * 256 + threadIdx.x;
  if (tid >= LAYERS * 2 * 4 * 2 * 64) return;
  const int lane = tid & 63, fi = tid >> 6;
  const int Kt = fi & 1, Mt = (fi >> 1) & 3, m = (fi >> 3) & 1, l = fi >> 4;
  const float* W = (m ? W_root : W_rel) + (size_t)l * HD * HD;
  const int col = lane & 15, quad = lane >> 4;
  const int jdim = Mt * 16 + col;
  unsigned pk[4];
#pragma unroll
  for (int w = 0; w < 4; ++w) {
    const int j0 = 2 * w, j1 = 2 * w + 1;
    const int d0 = ((j0 >> 2) * 2 + Kt) * 16 + quad * 4 + (j0 & 3);
    const int d1 = ((j1 >> 2) * 2 + Kt) * 16 + quad * 4 + (j1 & 3);
    pk[w] = f2bf_pk(W[(size_t)d0 * HD + jdim], W[(size_t)(d1) * HD + jdim]);
  }
  uint4 q; q.x = pk[0]; q.y = pk[1]; q.z = pk[2]; q.w = pk[3];
  *(uint4*)&wf[(size_t)tid * 4] = q;
}

// ---------------------------------------------------------------------------
// Kernel 2: pair adjacency -> B-frags in GLOBAL (r11-verified).
// ---------------------------------------------------------------------------
__global__ __launch_bounds__(256) void build_padj(const int* __restrict__ ei,
                                                  unsigned* __restrict__ adjf) {
  __shared__ unsigned cnt[4][48 * 24];
  const int lane = threadIdx.x & 63, wv = threadIdx.x >> 6;
  const int p = blockIdx.x * 4 + wv;
  const int col = lane & 15, quad = lane >> 4;
  unsigned* c = cnt[wv];
  for (int i = lane; i < 48 * 24; i += 64) c[i] = 0;
  asm volatile("s_waitcnt lgkmcnt(0)" ::: "memory");
  const int ebase = p * (2 * EDGES_PER);
  const int noff = p * PCOLS;
#pragma unroll
  for (int r = 0; r < 8; ++r) {
    const int e = ebase + r * 64 + lane;
    const int s = ei[e] - noff;           // src pair-col 0..45
    const int d = ei[E_TOT + e] - noff;   // dst pair-col 0..45
    atomicAdd(&c[d * 24 + (s >> 1)], 1u << ((s & 1) * 16));
  }
  asm volatile("s_waitcnt lgkmcnt(0)" ::: "memory");
#pragma unroll
  for (int Nt = 0; Nt < 3; ++Nt) {
    const int dst = col + 16 * Nt;
    const bool dok = dst < PCOLS;
#pragma unroll
    for (int Kt = 0; Kt < 2; ++Kt) {
      unsigned pk[4];
#pragma unroll
      for (int w = 0; w < 4; ++w) {
        const int s0 = Kt * 32 + quad * 8 + 2 * w;
        float v0 = 0.f, v1 = 0.f;
        if (dok && s0 < PCOLS) {
          const unsigned rd = c[dst * 24 + (s0 >> 1)];
          v0 = (float)(rd & 0xffffu);
          if (s0 + 1 < PCOLS) v1 = (float)(rd >> 16);
        }
        pk[w] = f2bf_pk(v0, v1);
      }
      uint4 q; q.x = pk[0]; q.y = pk[1]; q.z = pk[2]; q.w = pk[3];
      ((uint4*)adjf)[((size_t)p * 6 + Nt * 2 + Kt) * 64 + lane] = q;
    }
  }
}

// ---------------------------------------------------------------------------
// Kernel 3: wave = 1 graph PAIR; __launch_bounds__(256,3): reg cap 170 so
// acc + zpk + addresses fit in ARCH VGPRs (no forced 64/64 split -> no
// v_accvgpr_read/write traffic on LN/z/bias, no spills). r11 body otherwise.
// ---------------------------------------------------------------------------
__global__ __launch_bounds__(256, 3) void gcn_main(
    const float* __restrict__ x, const unsigned* __restrict__ adjf,
    const unsigned* __restrict__ wf,
    const float* __restrict__ W_enc, const float* __restrict__ b_enc,
    const float* __restrict__ ln_g, const float* __restrict__ ln_b,
    const float* __restrict__ b_rel, float* __restrict__ pooled) {
  __shared__ __align__(16) unsigned short sm[4 * HD * NS];   // 32768 B/block
  const int lane = threadIdx.x & 63, wv = threadIdx.x >> 6;
  const int p = blockIdx.x * 4 + wv;                         // pair id
  const int col = lane & 15, quad = lane >> 4;
  unsigned short* zt = sm + wv * (HD * NS);                  // 8192 B / wave

  // ---- prologue: zero ztr (pad slots must stay exact bf16 zero) ----
  {
    uint4 z4; z4.x = 0; z4.y = 0; z4.z = 0; z4.w = 0;
    for (int i = lane; i < (HD * NS * 2) / 16; i += 64) ((uint4*)zt)[i] = z4;
  }
  asm volatile("s_waitcnt lgkmcnt(0)" ::: "memory");

  // adjacency frag base pointers (loop-invariant)
  const uint4* ap  = (const uint4*)adjf + (size_t)p * 384 + lane;  // frags 0-3
  const uint4* ap4 = ap + 256;                                     // frags 4-5

  // ---- compact loop-invariant ztr addresses (u16 units) ----
  const int c7 = (col >> 1) & 7;
  const int ra0 = col * NS + ((quad ^ c7) << 3);
  const unsigned short* zA = zt + ra0;
  const unsigned short* zB = zt + (ra0 ^ 32);
  int wb[3][2];
#pragma unroll
  for (int Nt = 0; Nt < 3; ++Nt) {
    const int node = col + 16 * Nt;
    wb[Nt][0] = (quad * 4    ) * NS + (((node >> 3) ^ (quad * 2    )) << 3) + (node & 7);
    wb[Nt][1] = (quad * 4 + 2) * NS + (((node >> 3) ^ (quad * 2 + 1)) << 3) + (node & 7);
  }

  // ---- encoder: pair x rows contiguous (node_id = p*46 + paircol) ----
  f4v acc[4][3];
  {
    const float* xg = x + (size_t)p * PCOLS * INF;
    f4v xa[3][2];
    const f4v zz = {0.f, 0.f, 0.f, 0.f};
#pragma unroll
    for (int Nt = 0; Nt < 3; ++Nt) {
      const int c = col + 16 * Nt;
      if (c < PCOLS) {
        const float* xp = xg + (size_t)c * INF;
        xa[Nt][0] = *(const f4v*)xp;
        xa[Nt][1] = *(const f4v*)(xp + 4);
      } else { xa[Nt][0] = zz; xa[Nt][1] = zz; }
    }
#pragma unroll
    for (int Mt = 0; Mt < 4; ++Mt) {
      const f4v be = *(const f4v*)(b_enc + Mt * 16 + quad * 4);
      acc[Mt][0] = be; acc[Mt][1] = be; acc[Mt][2] = be;
#pragma unroll
      for (int i = 0; i < INF; ++i) {
        const f4v we = *(const f4v*)(W_enc + i * HD + Mt * 16 + quad * 4);
        acc[Mt][0] += we * xa[0][i >> 2][i & 3];
        acc[Mt][1] += we * xa[1][i >> 2][i & 3];
        acc[Mt][2] += we * xa[2][i >> 2][i & 3];
      }
    }
  }

#pragma unroll 1
  for (int l = 0; l < LAYERS; ++l) {
    const unsigned* wbase = wf + (size_t)l * (2 * 4 * 2 * 64 * 4);

    // ---- LayerNorm: one-pass E[h], E[h^2], 6 interleaved chains ----
    float mu[3], rs[3];
    {
      float sh[3], qh[3];
#pragma unroll
      for (int Nt = 0; Nt < 3; ++Nt) {
        f2v t = vlo(acc[0][Nt]) + vhi(acc[0][Nt]);
        t += vlo(acc[1][Nt]); t += vhi(acc[1][Nt]);
        t += vlo(acc[2][Nt]); t += vhi(acc[2][Nt]);
        t += vlo(acc[3][Nt]); t += vhi(acc[3][Nt]);
        f2v u = vlo(acc[0][Nt]) * vlo(acc[0][Nt]);
        u += vhi(acc[0][Nt]) * vhi(acc[0][Nt]);
        u += vlo(acc[1][Nt]) * vlo(acc[1][Nt]);
        u += vhi(acc[1][Nt]) * vhi(acc[1][Nt]);
        u += vlo(acc[2][Nt]) * vlo(acc[2][Nt]);
        u += vhi(acc[2][Nt]) * vhi(acc[2][Nt]);
        u += vlo(acc[3][Nt]) * vlo(acc[3][Nt]);
        u += vhi(acc[3][Nt]) * vhi(acc[3][Nt]);
        sh[Nt] = t[0] + t[1];
        qh[Nt] = u[0] + u[1];
      }
#pragma unroll
      for (int Nt = 0; Nt < 3; ++Nt) { sh[Nt] += __shfl_xor(sh[Nt], 16); qh[Nt] += __shfl_xor(qh[Nt], 16); }
#pragma unroll
      for (int Nt = 0; Nt < 3; ++Nt) { sh[Nt] += __shfl_xor(sh[Nt], 32); qh[Nt] += __shfl_xor(qh[Nt], 32); }
#pragma unroll
      for (int Nt = 0; Nt < 3; ++Nt) {
        mu[Nt] = sh[Nt] * (1.0f / HD);
        float var = fmaf(qh[Nt], (1.0f / HD), -mu[Nt] * mu[Nt]);
        var = fmaxf(var, 0.f);
        rs[Nt] = rsqrtf(var + 1e-5f);
      }
    }

    // ---- z = relu(LN(h)) -> zpk B-frags (k-permuted) + ztr scatter ----
    FragU zpk[2][3];
#pragma unroll
    for (int Kt = 0; Kt < 2; ++Kt) {
#pragma unroll
      for (int hi = 0; hi < 2; ++hi) {
        const int Mt = Kt + 2 * hi;
        const f4v gf  = *(const f4v*)(ln_g + l * HD + Mt * 16 + quad * 4);
        const f4v bfv = *(const f4v*)(ln_b + l * HD + Mt * 16 + quad * 4);
        const f2v gl = vlo(gf), gh = vhi(gf);
        const f2v bl = vlo(bfv), bh = vhi(bfv);
#pragma unroll
        for (int Nt = 0; Nt < 3; ++Nt) {
          const f2v sgl = gl * rs[Nt], sgh = gh * rs[Nt];
          const f2v tbl = bl - mu[Nt] * sgl, tbh = bh - mu[Nt] * sgh;
          const f2v zl = max0(vlo(acc[Mt][Nt]) * sgl + tbl);
          const f2v zh = max0(vhi(acc[Mt][Nt]) * sgh + tbh);
          zpk[Kt][Nt].u[hi * 2 + 0] = pk2_bf16(zl);
          zpk[Kt][Nt].u[hi * 2 + 1] = pk2_bf16(zh);
        }
      }
#pragma unroll
      for (int hi = 0; hi < 2; ++hi) {
        const int Mt = Kt + 2 * hi;
#pragma unroll
        for (int Nt = 0; Nt < 3; ++Nt)
#pragma unroll
          for (int r2 = 0; r2 < 2; ++r2) {
            const unsigned d = zpk[Kt][Nt].u[hi * 2 + r2];
            unsigned short* pz = zt + Mt * 1024 + wb[Nt][r2];
            pz[0]  = (unsigned short)d;
            pz[NS] = (unsigned short)(d >> 16);
          }
      }
    }

    // ---- Wo-GEMM (register B; overlaps ztr round-trip) ----
#pragma unroll
    for (int Kt = 0; Kt < 2; ++Kt)
#pragma unroll
      for (int Mt = 0; Mt < 4; ++Mt) {
        const s8v wo = *(const s8v*)&wbase[((((1 * 4) + Mt) * 2 + Kt) * 64 + lane) * 4];
#pragma unroll
        for (int Nt = 0; Nt < 3; ++Nt)
          acc[Mt][Nt] = __builtin_amdgcn_mfma_f32_16x16x32_bf16(wo, zpk[Kt][Nt].v, acc[Mt][Nt], 0, 0, 0);
      }

    // ---- adjacency B-frags (transient, live across the agg phase only) ----
    FragU adjB[3][2];
#pragma unroll
    for (int idx = 0; idx < 4; ++idx)
      adjB[idx >> 1][idx & 1].v = *(const s8v*)(ap + idx * 64);
    adjB[2][0].v = *(const s8v*)(ap4);
    adjB[2][1].v = *(const s8v*)(ap4 + 64);

    asm volatile("s_waitcnt lgkmcnt(0)" ::: "memory");

    // ---- agg + pack per Nt (ag dies immediately), then Wr-GEMM ----
    const f4v zzero = {0.f, 0.f, 0.f, 0.f};
#pragma unroll
    for (int Kt = 0; Kt < 2; ++Kt) {
      const s8v zaA0 = *(const s8v*)&zA[(Kt    ) * 1024];
      const s8v zaA1 = *(const s8v*)&zB[(Kt    ) * 1024];
      const s8v zaC0 = *(const s8v*)&zA[(Kt + 2) * 1024];
      const s8v zaC1 = *(const s8v*)&zB[(Kt + 2) * 1024];
      FragU apk[3];
#pragma unroll
      for (int Nt = 0; Nt < 3; ++Nt) {
        f4v agA = __builtin_amdgcn_mfma_f32_16x16x32_bf16(zaA0, adjB[Nt][0].v, zzero, 0, 0, 0);
        agA     = __builtin_amdgcn_mfma_f32_16x16x32_bf16(zaA1, adjB[Nt][1].v, agA,   0, 0, 0);
        f4v agC = __builtin_amdgcn_mfma_f32_16x16x32_bf16(zaC0, adjB[Nt][0].v, zzero, 0, 0, 0);
        agC     = __builtin_amdgcn_mfma_f32_16x16x32_bf16(zaC1, adjB[Nt][1].v, agC,   0, 0, 0);
        apk[Nt].u[0] = pk2_bf16(vlo(agA));
        apk[Nt].u[1] = pk2_bf16(vhi(agA));
        apk[Nt].u[2] = pk2_bf16(vlo(agC));
        apk[Nt].u[3] = pk2_bf16(vhi(agC));
      }
#pragma unroll
      for (int Mt = 0; Mt < 4; ++Mt) {
        const s8v wr = *(const s8v*)&wbase[((((0 * 4) + Mt) * 2 + Kt) * 64 + lane) * 4];
#pragma unroll
        for (int Nt = 0; Nt < 3; ++Nt)
          acc[Mt][Nt] = __builtin_amdgcn_mfma_f32_16x16x32_bf16(wr, apk[Nt].v, acc[Mt][Nt], 0, 0, 0);
      }
    }

    // ---- + b_rel ----
#pragma unroll
    for (int Mt = 0; Mt < 4; ++Mt) {
      const f4v brf = *(const f4v*)(b_rel + l * HD + Mt * 16 + quad * 4);
      const f2v bl = vlo(brf), bh = vhi(brf);
#pragma unroll
      for (int Nt = 0; Nt < 3; ++Nt) {
        const f2v al = vlo(acc[Mt][Nt]) + bl;
        const f2v ah = vhi(acc[Mt][Nt]) + bh;
        acc[Mt][Nt] = (f4v){al[0], al[1], ah[0], ah[1]};
      }
    }
  }

  // ---- pool: two graphs per pair, two-pass through the 8 KB ztr region ----
  float* hb = (float*)zt;   // 32 cols x 64 dims x 4B = 8192 B exactly
  asm volatile("s_waitcnt lgkmcnt(0)" ::: "memory");
#pragma unroll
  for (int Mt = 0; Mt < 4; ++Mt)
#pragma unroll
    for (int Nt = 0; Nt < 2; ++Nt)
      *(f4v*)&hb[(col + 16 * Nt) * HD + Mt * 16 + quad * 4] = acc[Mt][Nt];
  asm volatile("s_waitcnt lgkmcnt(0)" ::: "memory");
  float sA = 0.f, sB = 0.f;
#pragma unroll
  for (int c = 0; c < NG; ++c) sA += hb[c * HD + lane];          // cols 0-22 (gA)
#pragma unroll
  for (int c = NG; c < 32; ++c) sB += hb[c * HD + lane];         // cols 23-31
  asm volatile("s_waitcnt lgkmcnt(0)" ::: "memory");
#pragma unroll
  for (int Mt = 0; Mt < 4; ++Mt)                                 // cols 32-47 -> slots 0-15
    *(f4v*)&hb[col * HD + Mt * 16 + quad * 4] = acc[Mt][2];
  asm volatile("s_waitcnt lgkmcnt(0)" ::: "memory");
#pragma unroll
  for (int c = 0; c < PCOLS - 32; ++c) sB += hb[c * HD + lane];  // cols 32-45
  pooled[(size_t)(2 * p) * HD + lane] = sA;
  pooled[(size_t)(2 * p + 1) * HD + lane] = sB;
}

// ---------------------------------------------------------------------------
// Kernel 4: temporal mean (+pos) + MLP head (unchanged, verified)
// ---------------------------------------------------------------------------
__global__ __launch_bounds__(64) void head(
    const float* __restrict__ pooled, const float* __restrict__ pos,
    const float* __restrict__ W1, const float* __restrict__ b1,
    const float* __restrict__ W2, const float* __restrict__ b2,
    float* __restrict__ out) {
  __shared__ float sv[HD];
  __shared__ float sh1[HD];
  const int b = blockIdx.x, k = threadIdx.x;
  float v = 0.f;
#pragma unroll
  for (int tt = 0; tt < TWIN; ++tt) v += pooled[((size_t)(b * TWIN + tt)) * HD + k];
  float p = 0.f;
#pragma unroll
  for (int tt = 0; tt < TWIN; ++tt) p += pos[tt * HD + k];
  v = v * (1.0f / (NG * TWIN)) + p * (1.0f / TWIN);
  sv[k] = v;
  __syncthreads();
  float a = b1[k];
#pragma unroll
  for (int kk = 0; kk < HD; ++kk) a = fmaf(sv[kk], W1[kk * HD + k], a);
  a = fmaxf(a, 0.f);
  sh1[k] = a;
  __syncthreads();
  if (k < CLS) {
    float o = b2[k];
#pragma unroll
    for (int kk = 0; kk < HD; ++kk) o = fmaf(sh1[kk], W2[kk * CLS + k], o);
    out[(size_t)b * CLS + k] = o;
  }
}

// ---------------------------------------------------------------------------
extern "C" void kernel_launch(void* const* d_in, const int* in_sizes, int n_in,
                              void* d_out, int out_size, void* d_ws, size_t ws_size,
                              hipStream_t stream) {
  const float* x      = (const float*)d_in[0];
  const int*   ei     = (const int*)  d_in[1];
  const float* W_enc  = (const float*)d_in[3];
  const float* b_enc  = (const float*)d_in[4];
  const float* ln_g   = (const float*)d_in[5];
  const float* ln_b   = (const float*)d_in[6];
  const float* W_rel  = (const float*)d_in[7];
  const float* b_rel  = (const float*)d_in[8];
  const float* W_root = (const float*)d_in[9];
  const float* pos    = (const float*)d_in[10];
  const float* W1     = (const float*)d_in[11];
  const float* b1     = (const float*)d_in[12];
  const float* W2     = (const float*)d_in[13];
  const float* b2     = (const float*)d_in[14];
  float* out = (float*)d_out;

  // workspace: W frags 320 KB | pair adj frags 50.3 MB | pooled 4.2 MB
  char* pp = (char*)d_ws;
  unsigned* wfrag   = (unsigned*)pp;  pp += (size_t)LAYERS * 2 * 4 * 2 * 64 * 16;
  unsigned* adjfrag = (unsigned*)pp;  pp += (size_t)NPAIR * 6 * 64 * 16;
  float*    pooled  = (float*)pp;

  pack_w    <<<80, 256, 0, stream>>>(W_rel, W_root, wfrag);
  build_padj<<<NPAIR / 4, 256, 0, stream>>>(ei, adjfrag);
  gcn_main  <<<NPAIR / 4, 256, 0, stream>>>(x, adjfrag, wfrag, W_enc, b_enc,
                                            ln_g, ln_b, b_rel, pooled);
  head      <<<BATCH, 64, 0, stream>>>(pooled, pos, W1, b1, W2, b2, out);
}